// Round 1
// baseline (125.814 us; speedup 1.0000x reference)
//
#include <hip/hip_runtime.h>
#include <math.h>

// SACConv: B=8, C1=C2=16, K=3, S=1, H=W=64, HDIM=16, N=C1*K*K=144, L=4096
// out[b,l,c] = sum_j h[j]*q[c,j] + q[c,16]
//   q[c,j] = sum_o M[o][c*17+j]*p[o],  M[o][c*17+j]=fc2_w[c*144+o][j], col16=fc2_b
// Block = one image row (b,y): 64 locations, 256 threads, 512 blocks.

#define C1q 16
#define C2q 16
#define NPq 144
#define HD 16
#define KO 16
#define NCHUNK 9   // 144/16

__global__ __launch_bounds__(256, 2) void sacconv_kernel(
    const float* __restrict__ x,
    const float* __restrict__ fc1_w,
    const float* __restrict__ fc1_b,
    const float* __restrict__ fc2_w,
    const float* __restrict__ fc2_b,
    float* __restrict__ out)
{
    __shared__ float P[NPq][64];            // patches [o][loc]  36864 B
    __shared__ float Mbuf[KO * 16 * 20];    // 20480 B, overlapped with reduction scratch
    __shared__ float Hl[64][17];            // h per location (16 used, pad 17)

    // reduction scratch aliases Mbuf (stats phase finishes before M staging; barriers separate)
    float (*redA)[64] = (float(*)[64])(Mbuf);
    float (*redB)[64] = (float(*)[64])(Mbuf + 256);
    float (*redC)[64] = (float(*)[64])(Mbuf + 512);
    float (*redD)[64] = (float(*)[64])(Mbuf + 768);
    float (*sb)[8]    = (float(*)[8])(Mbuf + 1024);   // per-loc broadcast stats

    const int t   = threadIdx.x;
    const int blk = blockIdx.x;       // 512
    const int b   = blk >> 6;
    const int y   = blk & 63;
    const int l0  = y * 64;

    // ---------- load patches (zero-pad 'same') ----------
    {
        const int xcol = t & 63;
        const int grp  = t >> 6;
        for (int o = grp; o < NPq; o += 4) {
            int c1  = o / 9;
            int rem = o - c1 * 9;
            int i   = rem / 3;
            int jj  = rem - i * 3;
            int yy  = y + i - 1;
            int xx  = xcol + jj - 1;
            float v = 0.f;
            if (yy >= 0 && yy < 64 && xx >= 0 && xx < 64)
                v = x[((b * C1q + c1) * 64 + yy) * 64 + xx];
            P[o][xcol] = v;
        }
    }
    __syncthreads();

    const int loc  = t & 63;
    const int grp  = t >> 6;
    const int obeg = grp * 36, oend = obeg + 36;

    // ---------- pass 1: sum, max ----------
    {
        float s = 0.f, mx = -1e30f;
        for (int o = obeg; o < oend; ++o) {
            float v = P[o][loc];
            s += v; mx = fmaxf(mx, v);
        }
        redA[grp][loc] = s; redB[grp][loc] = mx;
    }
    __syncthreads();
    if (t < 64) {
        float s  = redA[0][t] + redA[1][t] + redA[2][t] + redA[3][t];
        float mx = fmaxf(fmaxf(redB[0][t], redB[1][t]), fmaxf(redB[2][t], redB[3][t]));
        sb[t][0] = s * (1.f / 144.f);
        sb[t][1] = mx;
    }
    __syncthreads();

    // ---------- pass 2: central moments 2,3,4 + sum exp ----------
    {
        float mu = sb[loc][0], mx = sb[loc][1];
        float m2 = 0.f, m3 = 0.f, m4 = 0.f, se = 0.f;
        for (int o = obeg; o < oend; ++o) {
            float v  = P[o][loc];
            float d  = v - mu;
            float d2 = d * d;
            m2 += d2; m3 += d2 * d; m4 += d2 * d2;
            se += __expf(v - mx);
        }
        redA[grp][loc] = m2; redB[grp][loc] = m3;
        redC[grp][loc] = m4; redD[grp][loc] = se;
    }
    __syncthreads();
    if (t < 64) {
        float m2 = redA[0][t] + redA[1][t] + redA[2][t] + redA[3][t];
        float m3 = redB[0][t] + redB[1][t] + redB[2][t] + redB[3][t];
        float m4 = redC[0][t] + redC[1][t] + redC[2][t] + redC[3][t];
        float Z  = redD[0][t] + redD[1][t] + redD[2][t] + redD[3][t];
        float var   = m2 * (1.f / 143.f);          // ddof=1
        float sigma = sqrtf(var) + 1e-6f;
        float is  = 1.f / sigma;
        float is2 = is * is;
        sb[t][2] = sigma;
        sb[t][3] = (m3 * (1.f / 144.f)) * is2 * is;         // skew
        sb[t][4] = (m4 * (1.f / 144.f)) * is2 * is2 - 3.f;  // kurtosis
        sb[t][5] = 1.f / Z;
    }
    __syncthreads();

    // ---------- pass 3: entropy partials ----------
    {
        float mx = sb[loc][1], invZ = sb[loc][5];
        float ent = 0.f;
        for (int o = obeg; o < oend; ++o) {
            float v  = P[o][loc];
            float pr = __expf(v - mx) * invZ;
            ent += pr * __logf(pr + 1e-6f);
        }
        redA[grp][loc] = ent;
    }
    __syncthreads();

    // ---------- h = relu(stats @ fc1_w^T + fc1_b) ----------
    {
        float ent = -(redA[0][loc] + redA[1][loc] + redA[2][loc] + redA[3][loc]);
        float s0 = sb[loc][0], s1 = sb[loc][2], s2 = sb[loc][3], s3 = sb[loc][4];
        for (int j = grp * 4; j < grp * 4 + 4; ++j) {
            const float* wr = fc1_w + j * 5;
            float hv = s0 * wr[0] + s1 * wr[1] + s2 * wr[2] + s3 * wr[3]
                     + ent * wr[4] + fc1_b[j];
            Hl[loc][j] = fmaxf(hv, 0.f);
        }
    }
    __syncthreads();

    // ---------- main GEMM: q[c, 0..16] for 4 locations per thread ----------
    const int c  = t >> 4;      // 0..15, 4 distinct values per wave (broadcast-friendly M reads)
    const int lg = t & 15;      // location group; locs = lg + 16r

    float acc[4][17];
#pragma unroll
    for (int r = 0; r < 4; ++r)
#pragma unroll
        for (int j = 0; j < 17; ++j) acc[r][j] = 0.f;

    for (int ch = 0; ch < NCHUNK; ++ch) {
        const int o0 = ch * KO;
        // stage M chunk: thread (cs = t>>4, ks = t&15) loads one fc2 row (16 w + bias)
        {
            const int cs = t >> 4, ks = t & 15;
            const int row = cs * NPq + o0 + ks;
            const float4* wr = (const float4*)(fc2_w + row * 16);
            float4 a0 = wr[0], a1 = wr[1], a2 = wr[2], a3 = wr[3];
            float bb = fc2_b[row];
            float* md = &Mbuf[(ks * 16 + cs) * 20];
            md[0]  = a0.x; md[1]  = a0.y; md[2]  = a0.z; md[3]  = a0.w;
            md[4]  = a1.x; md[5]  = a1.y; md[6]  = a1.z; md[7]  = a1.w;
            md[8]  = a2.x; md[9]  = a2.y; md[10] = a2.z; md[11] = a2.w;
            md[12] = a3.x; md[13] = a3.y; md[14] = a3.z; md[15] = a3.w;
            md[16] = bb;
        }
        __syncthreads();
#pragma unroll
        for (int ko = 0; ko < KO; ++ko) {
            const float* pr = &P[o0 + ko][0];
            float p0 = pr[lg], p1 = pr[lg + 16], p2 = pr[lg + 32], p3 = pr[lg + 48];
            const float* mr = &Mbuf[(ko * 16 + c) * 20];
#pragma unroll
            for (int j = 0; j < 17; ++j) {
                float mv = mr[j];
                acc[0][j] += p0 * mv;
                acc[1][j] += p1 * mv;
                acc[2][j] += p2 * mv;
                acc[3][j] += p3 * mv;
            }
        }
        __syncthreads();
    }

    // ---------- epilogue: fold h, write out[b][c][l] ----------
#pragma unroll
    for (int r = 0; r < 4; ++r) {
        const int lc = lg + 16 * r;
        float s = acc[r][16];
#pragma unroll
        for (int j = 0; j < 16; ++j) s += Hl[lc][j] * acc[r][j];
        out[(b * C2q + c) * 4096 + l0 + lc] = s;
    }
}

extern "C" void kernel_launch(void* const* d_in, const int* in_sizes, int n_in,
                              void* d_out, int out_size, void* d_ws, size_t ws_size,
                              hipStream_t stream) {
    const float* x     = (const float*)d_in[0];
    const float* fc1_w = (const float*)d_in[1];
    const float* fc1_b = (const float*)d_in[2];
    const float* fc2_w = (const float*)d_in[3];
    const float* fc2_b = (const float*)d_in[4];
    float* out = (float*)d_out;

    sacconv_kernel<<<512, 256, 0, stream>>>(x, fc1_w, fc1_b, fc2_w, fc2_b, out);
}